// Round 5
// baseline (476.049 us; speedup 1.0000x reference)
//
#include <hip/hip_runtime.h>
#include <stdint.h>

#define N_NODES 100000
#define N_EDGES 640000
#define R_REL   64
#define D_DIM   128
#define L_LAYERS 2

#define SCAN_CHUNK 1024
#define NBLK_SCAN ((N_NODES + SCAN_CHUNK - 1) / SCAN_CHUNK)   // 98

#define LDA 136   // 128 + 8 pad (bf16 elems)
#define LDT 264   // 256 + 8 pad
#define ECAP 1024 // staged edges per block (region [32*LDA, 32*LDT) = 8192 B)

typedef __attribute__((ext_vector_type(8))) short   short8;   // 8 bf16 MFMA frag
typedef __attribute__((ext_vector_type(8))) unsigned short ushort8;
typedef __attribute__((ext_vector_type(4))) unsigned short ushort4v;
typedef __attribute__((ext_vector_type(4))) float   f32x4;

__device__ __forceinline__ unsigned short f32_to_bf16(float f) {
  union { float f; uint32_t u; } v; v.f = f;
  uint32_t u = v.u;
  u += 0x7fffu + ((u >> 16) & 1u);   // RNE (finite inputs only)
  return (unsigned short)(u >> 16);
}
__device__ __forceinline__ float lo_bf(uint32_t p) {
  union { uint32_t u; float f; } v; v.u = p << 16; return v.f;
}
__device__ __forceinline__ float hi_bf(uint32_t p) {
  union { uint32_t u; float f; } v; v.u = p & 0xffff0000u; return v.f;
}

// ---------------------------------------------------------------------------
// CSR build: histogram -> 3-kernel exclusive scan -> slot scatter
// ---------------------------------------------------------------------------
__global__ __launch_bounds__(256)
void hist_kernel(const int* __restrict__ ei, int* __restrict__ deg) {
  int idx = blockIdx.x * 256 + threadIdx.x;
  atomicAdd(&deg[ei[N_EDGES + idx]], 1);
}

__global__ __launch_bounds__(256)
void scan_part1(const int* __restrict__ deg, int* __restrict__ partial) {
  __shared__ int lds[256];
  const int b = blockIdx.x, t = threadIdx.x;
  const int base = b * SCAN_CHUNK + t * 4;
  int s = 0;
  for (int k = 0; k < 4; ++k) { int i = base + k; s += (i < N_NODES) ? deg[i] : 0; }
  lds[t] = s; __syncthreads();
  for (int off = 128; off > 0; off >>= 1) {
    if (t < off) lds[t] += lds[t + off];
    __syncthreads();
  }
  if (t == 0) partial[b] = lds[0];
}

__global__ __launch_bounds__(128)
void scan_part2(int* __restrict__ partial, int* __restrict__ blockoff) {
  __shared__ int lds[128];
  const int t = threadIdx.x;
  const int v = (t < NBLK_SCAN) ? partial[t] : 0;
  lds[t] = v; __syncthreads();
  for (int off = 1; off < 128; off <<= 1) {
    int add = (t >= off) ? lds[t - off] : 0;
    __syncthreads();
    lds[t] += add;
    __syncthreads();
  }
  if (t < NBLK_SCAN) blockoff[t] = lds[t] - v;   // exclusive
}

__global__ __launch_bounds__(256)
void scan_part3(const int* __restrict__ deg, const int* __restrict__ blockoff,
                int* __restrict__ rowptr, int* __restrict__ cursor) {
  __shared__ int lds[256];
  const int b = blockIdx.x, t = threadIdx.x;
  const int base = b * SCAN_CHUNK + t * 4;
  int v[4]; int s = 0;
  for (int k = 0; k < 4; ++k) {
    int i = base + k;
    v[k] = (i < N_NODES) ? deg[i] : 0;
    s += v[k];
  }
  lds[t] = s; __syncthreads();
  for (int off = 1; off < 256; off <<= 1) {
    int add = (t >= off) ? lds[t - off] : 0;
    __syncthreads();
    lds[t] += add;
    __syncthreads();
  }
  int excl = lds[t] - s + blockoff[b];
  for (int k = 0; k < 4; ++k) {
    int i = base + k;
    if (i < N_NODES) { rowptr[i] = excl; cursor[i] = excl; excl += v[k]; }
  }
  if (b == 0 && t == 0) rowptr[N_NODES] = N_EDGES;
}

__global__ __launch_bounds__(256)
void scatter_kernel(const int* __restrict__ ei, const int* __restrict__ et,
                    int* __restrict__ cursor, int2* __restrict__ edges2) {
  int idx = blockIdx.x * 256 + threadIdx.x;
  int dst = ei[N_EDGES + idx];
  int slot = atomicAdd(&cursor[dst], 1);
  edges2[slot] = make_int2(ei[idx], et[idx]);
}

// ---------------------------------------------------------------------------
// prep: blocks [0,128): gamma/beta -> packed bf16 gbb.
//       blocks [128,384): weight f32->bf16 conversion.
// gbb layout per type t: 16 groups x (8 gamma bf16, 8 beta bf16) = 256 ushorts.
// ---------------------------------------------------------------------------
__global__ __launch_bounds__(256)
void prep_kernel(const float* __restrict__ rel_emb,
                 const float* __restrict__ rmw0, const float* __restrict__ rmb0,
                 const float* __restrict__ rmw1, const float* __restrict__ rmb1,
                 const float* __restrict__ rmw2, const float* __restrict__ rmb2,
                 const float* __restrict__ rmw3, const float* __restrict__ rmb3,
                 unsigned short* __restrict__ gbb,
                 const float* __restrict__ Ww, const float* __restrict__ mw0,
                 const float* __restrict__ mw1,
                 unsigned short* __restrict__ Wwb, unsigned short* __restrict__ mw0b,
                 unsigned short* __restrict__ mw1b) {
  if (blockIdx.x >= 128) {
    int i = (blockIdx.x - 128) * 256 + threadIdx.x;   // 0..65535
    if (i < L_LAYERS * D_DIM * D_DIM)     Wwb[i]  = f32_to_bf16(Ww[i]);
    if (i < L_LAYERS * 2 * D_DIM * D_DIM) mw0b[i] = f32_to_bf16(mw0[i]);
    if (i < L_LAYERS * 2 * D_DIM * D_DIM) mw1b[i] = f32_to_bf16(mw1[i]);
    return;
  }
  __shared__ float bufA[2 * D_DIM];
  __shared__ float bufB[2 * D_DIM];
  const int l = blockIdx.x >> 6;
  const int r = blockIdx.x & 63;
  const int j = threadIdx.x;   // 0..255

  if (j < D_DIM) bufA[j] = rel_emb[(l * R_REL + r) * D_DIM + j];
  __syncthreads();
  {
    const float* w = rmw0 + ((size_t)l * 2 * D_DIM + j) * D_DIM;
    float s = rmb0[l * 2 * D_DIM + j];
    for (int k = 0; k < D_DIM; k += 4) {
      float4 wv = *(const float4*)(w + k);
      s += wv.x * bufA[k] + wv.y * bufA[k + 1] + wv.z * bufA[k + 2] + wv.w * bufA[k + 3];
    }
    bufB[j] = fmaxf(s, 0.0f);
  }
  __syncthreads();
  {
    const float* w = rmw1 + ((size_t)l * 2 * D_DIM + j) * 2 * D_DIM;
    float s = rmb1[l * 2 * D_DIM + j];
    for (int k = 0; k < 2 * D_DIM; k += 4) {
      float4 wv = *(const float4*)(w + k);
      s += wv.x * bufB[k] + wv.y * bufB[k + 1] + wv.z * bufB[k + 2] + wv.w * bufB[k + 3];
    }
    __syncthreads();
    bufA[j] = fmaxf(s, 0.0f);
  }
  __syncthreads();
  {
    const float* w = rmw2 + ((size_t)l * 2 * D_DIM + j) * 2 * D_DIM;
    float s = rmb2[l * 2 * D_DIM + j];
    for (int k = 0; k < 2 * D_DIM; k += 4) {
      float4 wv = *(const float4*)(w + k);
      s += wv.x * bufA[k] + wv.y * bufA[k + 1] + wv.z * bufA[k + 2] + wv.w * bufA[k + 3];
    }
    __syncthreads();
    bufB[j] = fmaxf(s, 0.0f);
  }
  __syncthreads();
  {
    const float* w = rmw3 + ((size_t)l * 2 * D_DIM + j) * 2 * D_DIM;
    float s = rmb3[l * 2 * D_DIM + j];
    for (int k = 0; k < 2 * D_DIM; k += 4) {
      float4 wv = *(const float4*)(w + k);
      s += wv.x * bufB[k] + wv.y * bufB[k + 1] + wv.z * bufB[k + 2] + wv.w * bufB[k + 3];
    }
    const int t = l * R_REL + r;
    if (j < D_DIM) gbb[t * 256 + (j >> 3) * 16 + (j & 7)] = f32_to_bf16(s);         // gamma
    else { int cb = j - D_DIM;
           gbb[t * 256 + (cb >> 3) * 16 + 8 + (cb & 7)] = f32_to_bf16(s); }         // beta
  }
}

// ---------------------------------------------------------------------------
// xw = bf16( x @ Ww^T + Wb )  (N x 128). bf16 weights, direct short8 loads.
// ---------------------------------------------------------------------------
__global__ __launch_bounds__(256)
void xw_kernel(const float* __restrict__ x,
               const unsigned short* __restrict__ Wwb,  // 128x128 bf16 layer slice
               const float* __restrict__ Wb,            // 128
               unsigned short* __restrict__ xwb) {
  __shared__ unsigned short a_lds[32 * LDA];
  const int tid = threadIdx.x;
  const int m0 = blockIdx.x * 32;

  for (int i = tid; i < 1024; i += 256) {
    int row = i >> 5, ch = i & 31;
    float4 v = *(const float4*)&x[(m0 + row) * D_DIM + ch * 4];
    ushort4v s;
    s[0] = f32_to_bf16(v.x); s[1] = f32_to_bf16(v.y);
    s[2] = f32_to_bf16(v.z); s[3] = f32_to_bf16(v.w);
    *(ushort4v*)&a_lds[row * LDA + ch * 4] = s;
  }
  __syncthreads();

  const int wave = tid >> 6, lane = tid & 63;
  const int lrow = lane & 15, quad = lane >> 4;
  const int n0 = wave * 32;

  f32x4 acc[2][2] = {};
  for (int ks = 0; ks < 128; ks += 32) {
    short8 a0 = *(const short8*)&a_lds[lrow * LDA + ks + quad * 8];
    short8 a1 = *(const short8*)&a_lds[(16 + lrow) * LDA + ks + quad * 8];
    short8 b0 = *(const short8*)&Wwb[(n0 + lrow) * D_DIM + ks + quad * 8];
    short8 b1 = *(const short8*)&Wwb[(n0 + 16 + lrow) * D_DIM + ks + quad * 8];
    acc[0][0] = __builtin_amdgcn_mfma_f32_16x16x32_bf16(a0, b0, acc[0][0], 0, 0, 0);
    acc[0][1] = __builtin_amdgcn_mfma_f32_16x16x32_bf16(a0, b1, acc[0][1], 0, 0, 0);
    acc[1][0] = __builtin_amdgcn_mfma_f32_16x16x32_bf16(a1, b0, acc[1][0], 0, 0, 0);
    acc[1][1] = __builtin_amdgcn_mfma_f32_16x16x32_bf16(a1, b1, acc[1][1], 0, 0, 0);
  }

  for (int mt = 0; mt < 2; ++mt)
    for (int nt = 0; nt < 2; ++nt)
      for (int rr = 0; rr < 4; ++rr) {
        int row = mt * 16 + quad * 4 + rr;
        int col = n0 + nt * 16 + lrow;
        xwb[(size_t)(m0 + row) * D_DIM + col] = f32_to_bf16(acc[mt][nt][rr] + Wb[col]);
      }
}

// ---------------------------------------------------------------------------
// Fused gather + node MLP. Block = 32 nodes, 4 waves.
// Phase A0: stage rowptr slice + contiguous CSR edge slice into LDS.
// Phase A:  each 16-lane quarter owns one node (8 cols/lane, 16B loads);
//           4 edge-walks concurrent per wave, 2-deep software pipeline
//           -> 8 edges in flight. o=(1+eps)x+aggr -> bf16 A-tile row.
// Phase B:  t = relu(o @ w0^T + b0) -> LDS (overlay, stride LDT).
// Phase C:  y = t @ w1^T + b1 -> global.
// ---------------------------------------------------------------------------
__global__ __launch_bounds__(256)
void gather_mlp_kernel(const int2* __restrict__ edges2, const int* __restrict__ rowptr,
                       const float* __restrict__ x, const unsigned short* __restrict__ xwb,
                       const unsigned short* __restrict__ gbb,
                       const float* __restrict__ eps,
                       const unsigned short* __restrict__ w0b, const float* __restrict__ b0,
                       const unsigned short* __restrict__ w1b, const float* __restrict__ b1,
                       float* __restrict__ y) {
  __shared__ unsigned short u_lds[32 * LDT];   // 16896 B, phases overlay
  __shared__ int rp_lds[33];
  unsigned short* a_lds = u_lds;               // stride LDA (phase A write / B read)
  unsigned short* t_lds = u_lds;               // stride LDT (phase B write / C read)
  int2* es = (int2*)(u_lds + 32 * LDA);        // phase-A-only region, 1024 edges

  const int tid = threadIdx.x;
  const int m0 = blockIdx.x * 32;
  const int wave = tid >> 6, lane = tid & 63;
  const float e1v = 1.0f + eps[0];

  // ---- phase A0: stage rowptr slice + edge slice
  if (tid < 33) rp_lds[tid] = rowptr[m0 + tid];
  const int beg0 = rowptr[m0];
  const int nE = rowptr[m0 + 32] - beg0;
  for (int i = tid; i < nE && i < ECAP; i += 256) es[i] = edges2[beg0 + i];
  __syncthreads();

  // ---- phase A: quarter-wave per node, 2 rounds, 2-deep pipeline
  const int q = lane >> 4;           // quarter 0..3
  const int s = lane & 15;           // lane-in-quarter
  const int c = s * 8;               // 8 cols per lane
  for (int round = 0; round < 2; ++round) {
    const int row  = wave * 8 + round * 4 + q;
    const int node = m0 + row;
    const int beg = rp_lds[row], end = rp_lds[row + 1];
    float acc[8] = {};

    int e = beg;
    bool a0 = e < end;
    ushort8 xu, gg, bb;
    if (a0) {
      int le = e - beg0;
      int2 ed = (le < ECAP) ? es[le] : edges2[e];
      xu = *(const ushort8*)&xwb[(size_t)ed.x * D_DIM + c];
      gg = *(const ushort8*)&gbb[ed.y * 256 + s * 16];
      bb = *(const ushort8*)&gbb[ed.y * 256 + s * 16 + 8];
    }
    while (__ballot(a0)) {
      const int e1 = e + 1;
      const bool a1 = e1 < end;
      ushort8 xu1, gg1, bb1;
      if (a1) {
        int le = e1 - beg0;
        int2 ed = (le < ECAP) ? es[le] : edges2[e1];
        xu1 = *(const ushort8*)&xwb[(size_t)ed.x * D_DIM + c];
        gg1 = *(const ushort8*)&gbb[ed.y * 256 + s * 16];
        bb1 = *(const ushort8*)&gbb[ed.y * 256 + s * 16 + 8];
      }
      if (a0) {
        union { ushort8 v; uint32_t u[4]; } X, G, B;
        X.v = xu; G.v = gg; B.v = bb;
        for (int k = 0; k < 4; ++k) {
          acc[2*k]   = fmaf(lo_bf(G.u[k]), lo_bf(X.u[k]), acc[2*k])   + lo_bf(B.u[k]);
          acc[2*k+1] = fmaf(hi_bf(G.u[k]), hi_bf(X.u[k]), acc[2*k+1]) + hi_bf(B.u[k]);
        }
      }
      xu = xu1; gg = gg1; bb = bb1; a0 = a1; e = e1;
    }

    float4 xo0 = *(const float4*)&x[(size_t)node * D_DIM + c];
    float4 xo1 = *(const float4*)&x[(size_t)node * D_DIM + c + 4];
    ushort8 o8;
    o8[0] = f32_to_bf16(e1v * xo0.x + acc[0]);
    o8[1] = f32_to_bf16(e1v * xo0.y + acc[1]);
    o8[2] = f32_to_bf16(e1v * xo0.z + acc[2]);
    o8[3] = f32_to_bf16(e1v * xo0.w + acc[3]);
    o8[4] = f32_to_bf16(e1v * xo1.x + acc[4]);
    o8[5] = f32_to_bf16(e1v * xo1.y + acc[5]);
    o8[6] = f32_to_bf16(e1v * xo1.z + acc[6]);
    o8[7] = f32_to_bf16(e1v * xo1.w + acc[7]);
    *(ushort8*)&a_lds[row * LDA + c] = o8;
  }
  __syncthreads();

  const int lrow = lane & 15, quad = lane >> 4;

  // ---- phase B: t = relu(o @ w0^T + b0); wave covers cols [wave*64, +64)
  {
    const int n0 = wave * 64;
    f32x4 acc[2][4] = {};
    for (int ks = 0; ks < 128; ks += 32) {
      short8 a0 = *(const short8*)&a_lds[lrow * LDA + ks + quad * 8];
      short8 a1 = *(const short8*)&a_lds[(16 + lrow) * LDA + ks + quad * 8];
      for (int nt = 0; nt < 4; ++nt) {
        short8 b = *(const short8*)&w0b[(n0 + nt * 16 + lrow) * D_DIM + ks + quad * 8];
        acc[0][nt] = __builtin_amdgcn_mfma_f32_16x16x32_bf16(a0, b, acc[0][nt], 0, 0, 0);
        acc[1][nt] = __builtin_amdgcn_mfma_f32_16x16x32_bf16(a1, b, acc[1][nt], 0, 0, 0);
      }
    }
    __syncthreads();   // all waves done reading A-tile before overlay write
    for (int mt = 0; mt < 2; ++mt)
      for (int nt = 0; nt < 4; ++nt)
        for (int rr = 0; rr < 4; ++rr) {
          int row = mt * 16 + quad * 4 + rr;
          int col = n0 + nt * 16 + lrow;
          float v = acc[mt][nt][rr] + b0[col];
          t_lds[row * LDT + col] = f32_to_bf16(fmaxf(v, 0.0f));
        }
  }
  __syncthreads();

  // ---- phase C: y = t @ w1^T + b1; wave covers cols [wave*32, +32)
  {
    const int n0 = wave * 32;
    f32x4 acc[2][2] = {};
    for (int ks = 0; ks < 256; ks += 32) {
      short8 a0 = *(const short8*)&t_lds[lrow * LDT + ks + quad * 8];
      short8 a1 = *(const short8*)&t_lds[(16 + lrow) * LDT + ks + quad * 8];
      for (int nt = 0; nt < 2; ++nt) {
        short8 b = *(const short8*)&w1b[(n0 + nt * 16 + lrow) * 2 * D_DIM + ks + quad * 8];
        acc[0][nt] = __builtin_amdgcn_mfma_f32_16x16x32_bf16(a0, b, acc[0][nt], 0, 0, 0);
        acc[1][nt] = __builtin_amdgcn_mfma_f32_16x16x32_bf16(a1, b, acc[1][nt], 0, 0, 0);
      }
    }
    for (int mt = 0; mt < 2; ++mt)
      for (int nt = 0; nt < 2; ++nt)
        for (int rr = 0; rr < 4; ++rr) {
          int row = mt * 16 + quad * 4 + rr;
          int col = n0 + nt * 16 + lrow;
          y[(size_t)(m0 + row) * D_DIM + col] = acc[mt][nt][rr] + b1[col];
        }
  }
}

// ---------------------------------------------------------------------------
extern "C" void kernel_launch(void* const* d_in, const int* in_sizes, int n_in,
                              void* d_out, int out_size, void* d_ws, size_t ws_size,
                              hipStream_t stream) {
  const int*   ei      = (const int*)d_in[0];
  const int*   et      = (const int*)d_in[1];
  const float* embed   = (const float*)d_in[2];
  const float* rel_emb = (const float*)d_in[3];
  const float* rmw0 = (const float*)d_in[4];  const float* rmb0 = (const float*)d_in[5];
  const float* rmw1 = (const float*)d_in[6];  const float* rmb1 = (const float*)d_in[7];
  const float* rmw2 = (const float*)d_in[8];  const float* rmb2 = (const float*)d_in[9];
  const float* rmw3 = (const float*)d_in[10]; const float* rmb3 = (const float*)d_in[11];
  const float* Ww   = (const float*)d_in[12]; const float* Wb   = (const float*)d_in[13];
  const float* mw0  = (const float*)d_in[14]; const float* mb0  = (const float*)d_in[15];
  const float* mw1  = (const float*)d_in[16]; const float* mb1  = (const float*)d_in[17];
  const float* eps  = (const float*)d_in[18];
  float* out = (float*)d_out;

  // workspace layout
  float*          W1   = (float*)d_ws;                          // N*D f32
  unsigned short* xwb  = (unsigned short*)(W1 + (size_t)N_NODES * D_DIM);  // N*D bf16
  unsigned short* gbb  = xwb + (size_t)N_NODES * D_DIM;         // L*R*256 bf16
  unsigned short* Wwb  = gbb + L_LAYERS * R_REL * 256;          // L*128*128
  unsigned short* mw0b = Wwb + L_LAYERS * D_DIM * D_DIM;        // L*256*128
  unsigned short* mw1b = mw0b + L_LAYERS * 2 * D_DIM * D_DIM;   // L*128*256
  int*   deg     = (int*)(mw1b + L_LAYERS * 2 * D_DIM * D_DIM); // N
  int*   rowptr  = deg + N_NODES;                               // N+1
  int*   cursor  = rowptr + N_NODES + 1;                        // N
  int*   partial = cursor + N_NODES;                            // NBLK_SCAN
  int*   blockoff= partial + NBLK_SCAN;                         // NBLK_SCAN
  int2*  edges2  = (int2*)(blockoff + NBLK_SCAN + 1);           // E int2

  // ---- one-shot preprocessing
  hipMemsetAsync(deg, 0, N_NODES * sizeof(int), stream);
  hist_kernel<<<N_EDGES / 256, 256, 0, stream>>>(ei, deg);
  scan_part1<<<NBLK_SCAN, 256, 0, stream>>>(deg, partial);
  scan_part2<<<1, 128, 0, stream>>>(partial, blockoff);
  scan_part3<<<NBLK_SCAN, 256, 0, stream>>>(deg, blockoff, rowptr, cursor);
  scatter_kernel<<<N_EDGES / 256, 256, 0, stream>>>(ei, et, cursor, edges2);
  prep_kernel<<<384, 256, 0, stream>>>(rel_emb, rmw0, rmb0, rmw1, rmb1,
                                       rmw2, rmb2, rmw3, rmb3, gbb,
                                       Ww, mw0, mw1, Wwb, mw0b, mw1b);

  const int gN = N_NODES / 32;        // 3125

  // ---- layer 0: x = embed -> xwb -> fused gather+mlp -> W1
  xw_kernel<<<gN, 256, 0, stream>>>(embed, Wwb, Wb, xwb);
  gather_mlp_kernel<<<gN, 256, 0, stream>>>(edges2, rowptr, embed, xwb, gbb, eps,
                                            mw0b, mb0, mw1b, mb1, W1);

  // ---- layer 1: x = W1 -> xwb -> fused gather+mlp -> d_out
  xw_kernel<<<gN, 256, 0, stream>>>(W1, Wwb + D_DIM * D_DIM, Wb + D_DIM, xwb);
  gather_mlp_kernel<<<gN, 256, 0, stream>>>(edges2, rowptr, W1, xwb,
                                            gbb + R_REL * 256, eps + 1,
                                            mw0b + 2 * D_DIM * D_DIM, mb0 + 2 * D_DIM,
                                            mw1b + 2 * D_DIM * D_DIM, mb1 + D_DIM, out);
}